// Round 7
// baseline (301.675 us; speedup 1.0000x reference)
//
#include <hip/hip_runtime.h>
#include <math.h>

// Problem constants
#define NPTS 200000
#define LNEPS 1e-6f

typedef unsigned short u16;
typedef __attribute__((ext_vector_type(4))) float  f4;
typedef __attribute__((ext_vector_type(8))) short  s8;
typedef __attribute__((ext_vector_type(4))) short  s4;

__device__ __forceinline__ u16 f2b(float f) {
    union { float f; unsigned u; } v; v.f = f;
    unsigned r = v.u + 0x7fffu + ((v.u >> 16) & 1u);   // round-to-nearest-even
    return (u16)(r >> 16);
}

// tanh-form GELU via HW exp2/rcp (~1e-3 max dev from exact erf-GELU).
__device__ __forceinline__ float gelu_f(float v) {
    float u = v * (0.7978845608028654f + 0.035677408136300125f * v * v);
    u = fminf(u, 15.0f);
    float e = __builtin_amdgcn_exp2f(u * 2.8853900817779268f);  // exp(2u)
    return 0.5f * v * (1.0f + (e - 1.0f) * __builtin_amdgcn_rcpf(e + 1.0f));
}

// ---------------------------------------------------------------------------
// K0: repack weights to bf16 MFMA B-fragment order. (unchanged)
// ---------------------------------------------------------------------------
__global__ __launch_bounds__(256) void k0_convw(
    const float* __restrict__ W1, const float* __restrict__ W2,
    const float* __restrict__ W3,
    u16* __restrict__ W1f, u16* __restrict__ W2f, u16* __restrict__ W3f,
    u16* __restrict__ h1)
{
    int t = blockIdx.x * 256 + threadIdx.x;
    if (t < 16384) {                       // W1f: nt(4) ks(8) l(64) j(8)
        int j = t & 7, l = (t >> 3) & 63, ks = (t >> 9) & 7, nt = t >> 12;
        int k = 32 * ks + (l >> 4) * 8 + j;
        int n = 16 * nt + (l & 15);
        W1f[t] = f2b(W1[k * 64 + n]);
    }
    if (t < 36864) {                       // W2f: kk(9) x { nt(4) ks(2) l(64) j(8) }
        int kk = t >> 12;
        int r = t & 4095;
        int j = r & 7, l = (r >> 3) & 63, ks = (r >> 9) & 1, nt = r >> 10;
        int k = 32 * ks + (l >> 4) * 8 + j;
        int n = 16 * nt + (l & 15);
        W2f[t] = f2b(W2[(kk * 64 + k) * 64 + n]);
    }
    if (t < 16384) {                       // W3f: nt(16) ks(2) l(64) j(8)
        int j = t & 7, l = (t >> 3) & 63, ks = (t >> 9) & 1, nt = t >> 10;
        int k = 32 * ks + (l >> 4) * 8 + j;
        int n = 16 * nt + (l & 15);
        W3f[t] = f2b(W3[k * 256 + n]);
    }
    if (t < 64) h1[(long)NPTS * 64 + t] = 0;   // sentinel zero row
}

// ---------------------------------------------------------------------------
// K1 (PROBE x3): conv1 + LN + GELU -> h1.  Internal rep-loop x3 with memory
// clobber per rep so the whole body re-executes; dispatch time ~= 3x real k1.
// ---------------------------------------------------------------------------
__global__ __launch_bounds__(256) void k1_conv1(
    const float* __restrict__ x, const u16* __restrict__ W1f,
    const float* __restrict__ g1, const float* __restrict__ b1,
    u16* __restrict__ h1)
{
    __shared__ __align__(16) u16 xt[64][256];   // 32 KB, rows XOR-swizzled
    int tid = threadIdx.x;
    long base = (long)blockIdx.x * 64;

    for (int rep = 0; rep < 3; ++rep) {
        asm volatile("" ::: "memory");   // defeat cross-rep CSE/hoisting

        #pragma unroll
        for (int p = 0; p < 16; ++p) {
            int row  = p * 4 + (tid >> 6);
            int col4 = (tid & 63) * 4;
            f4 v = *(const f4*)(x + (base + row) * 256 + col4);
            s4 bv;
            bv[0] = (short)f2b(v[0]); bv[1] = (short)f2b(v[1]);
            bv[2] = (short)f2b(v[2]); bv[3] = (short)f2b(v[3]);
            int byte = (col4 * 2) ^ ((row & 7) << 4);
            *(s4*)((char*)&xt[row][0] + byte) = bv;
        }
        __syncthreads();

        int w = tid >> 6, l = tid & 63, lg = l >> 4, lr = l & 15;
        int arow = w * 16 + lr;
        long mbase = base + w * 16;

        f4 acc[4] = {};
        #pragma unroll
        for (int ks = 0; ks < 8; ++ks) {
            int byte = ((ks * 64 + lg * 16)) ^ ((arow & 7) << 4);
            s8 a = *(const s8*)((const char*)&xt[arow][0] + byte);
            #pragma unroll
            for (int nt = 0; nt < 4; ++nt) {
                s8 b = *(const s8*)(W1f + ((nt * 8 + ks) * 64 + l) * 8);
                acc[nt] = __builtin_amdgcn_mfma_f32_16x16x32_bf16(a, b, acc[nt], 0, 0, 0);
            }
        }

        #pragma unroll
        for (int r = 0; r < 4; ++r) {
            float sv = 0.f, qv = 0.f;
            #pragma unroll
            for (int nt = 0; nt < 4; ++nt) { float v = acc[nt][r]; sv += v; qv += v * v; }
            #pragma unroll
            for (int m = 1; m < 16; m <<= 1) { sv += __shfl_xor(sv, m); qv += __shfl_xor(qv, m); }
            float mu  = sv * (1.0f / 64.0f);
            float var = qv * (1.0f / 64.0f) - mu * mu;
            float rs  = rsqrtf(var + LNEPS);
            long row = mbase + lg * 4 + r;
            #pragma unroll
            for (int nt = 0; nt < 4; ++nt) {
                int col = 16 * nt + lr;
                float v = (acc[nt][r] - mu) * rs * g1[col] + b1[col];
                h1[row * 64 + col] = f2b(gelu_f(v));
            }
        }
        __syncthreads();   // WAR: next rep restages xt
    }
}

// ---------------------------------------------------------------------------
// K2a (PROBE x2): gather + conv2 + LN + GELU -> h2.  Register-gather form
// (R3), internal rep-loop x2; dispatch time ~= 2x real k2a -> should crack
// the top-5 cutoff (~119us) if k2a >= ~60us, exposing its counters.
// ---------------------------------------------------------------------------
__global__ __launch_bounds__(256, 4) void k2a_conv2(
    const u16* __restrict__ h1, const u16* __restrict__ W2f,
    const float* __restrict__ g2, const float* __restrict__ b2,
    const int* __restrict__ nidx, u16* __restrict__ h2)
{
    int tid = threadIdx.x;
    int w = tid >> 6, l = tid & 63, lg = l >> 4, lr = l & 15;
    long base = (long)blockIdx.x * 64 + w * 16;
    long rowa = base + lr;

    for (int rep = 0; rep < 2; ++rep) {
        asm volatile("" ::: "memory");   // defeat cross-rep CSE/hoisting

        int idxs[9];
        #pragma unroll
        for (int k = 0; k < 9; ++k) idxs[k] = nidx[(long)k * NPTS + rowa];

        s8 afr[9][2];
        #pragma unroll
        for (int k = 0; k < 9; ++k) {
            const u16* arow = h1 + (long)idxs[k] * 64;
            afr[k][0] = *(const s8*)(arow + lg * 8);
            afr[k][1] = *(const s8*)(arow + 32 + lg * 8);
        }

        f4 acc2[4] = {};
        #pragma unroll
        for (int k = 0; k < 9; ++k) {
            #pragma unroll
            for (int ks = 0; ks < 2; ++ks) {
                #pragma unroll
                for (int nt = 0; nt < 4; ++nt) {
                    s8 b = *(const s8*)(W2f + (long)k * 4096 + ((nt * 2 + ks) * 64 + l) * 8);
                    acc2[nt] = __builtin_amdgcn_mfma_f32_16x16x32_bf16(afr[k][ks], b, acc2[nt], 0, 0, 0);
                }
            }
        }

        #pragma unroll
        for (int r = 0; r < 4; ++r) {
            float sv = 0.f, qv = 0.f;
            #pragma unroll
            for (int nt = 0; nt < 4; ++nt) { float v = acc2[nt][r]; sv += v; qv += v * v; }
            #pragma unroll
            for (int m = 1; m < 16; m <<= 1) { sv += __shfl_xor(sv, m); qv += __shfl_xor(qv, m); }
            float mu  = sv * (1.0f / 64.0f);
            float var = qv * (1.0f / 64.0f) - mu * mu;
            float rs  = rsqrtf(var + LNEPS);
            long row = base + lg * 4 + r;
            #pragma unroll
            for (int nt = 0; nt < 4; ++nt) {
                int col = 16 * nt + lr;
                float v = (acc2[nt][r] - mu) * rs * g2[col] + b2[col];
                h2[row * 64 + col] = f2b(gelu_f(v));
            }
        }
    }
}

// ---------------------------------------------------------------------------
// K2b: conv3 (h2 @ W3) + LN(256) + residual(x) + GELU -> out.  (x1, unchanged)
// ---------------------------------------------------------------------------
__global__ __launch_bounds__(256, 3) void k2b_conv3(
    const u16* __restrict__ h2, const u16* __restrict__ W3f,
    const float* __restrict__ x,
    const float* __restrict__ g3, const float* __restrict__ b3,
    float* __restrict__ out)
{
    __shared__ __align__(16) float ot[4][4][264];   // [wave][row][col], +8 pad
    int tid = threadIdx.x;
    int w = tid >> 6, l = tid & 63, lg = l >> 4, lr = l & 15;
    long base = (long)blockIdx.x * 64 + w * 16;

    const u16* arow = h2 + (base + lr) * 64;
    s8 a0 = *(const s8*)(arow + lg * 8);
    s8 a1 = *(const s8*)(arow + 32 + lg * 8);

    f4 acc3[16] = {};
    #pragma unroll
    for (int nt = 0; nt < 16; ++nt) {
        s8 b0 = *(const s8*)(W3f + ((nt * 2 + 0) * 64 + l) * 8);
        s8 b1 = *(const s8*)(W3f + ((nt * 2 + 1) * 64 + l) * 8);
        acc3[nt] = __builtin_amdgcn_mfma_f32_16x16x32_bf16(a0, b0, acc3[nt], 0, 0, 0);
        acc3[nt] = __builtin_amdgcn_mfma_f32_16x16x32_bf16(a1, b1, acc3[nt], 0, 0, 0);
    }

    #pragma unroll
    for (int r = 0; r < 4; ++r) {
        float sv = 0.f, qv = 0.f;
        #pragma unroll
        for (int nt = 0; nt < 16; ++nt) { float v = acc3[nt][r]; sv += v; qv += v * v; }
        #pragma unroll
        for (int m = 1; m < 16; m <<= 1) { sv += __shfl_xor(sv, m); qv += __shfl_xor(qv, m); }
        float mu  = sv * (1.0f / 256.0f);
        float var = qv * (1.0f / 256.0f) - mu * mu;
        float rs  = rsqrtf(var + LNEPS);

        #pragma unroll
        for (int nt = 0; nt < 16; ++nt) {
            int col = 16 * nt + lr;
            ot[w][lg][col] = (acc3[nt][r] - mu) * rs * g3[col] + b3[col];
        }
        __syncthreads();

        int rsel = l >> 4;
        long gr = (long)blockIdx.x * 64 + w * 16 + rsel * 4 + r;
        const float* xr = x + gr * 256;
        float* outr = out + gr * 256;
        int c0 = (l & 15) * 4;
        #pragma unroll
        for (int c = 0; c < 4; ++c) {
            int col = c0 + 64 * c;
            f4 lv = *(const f4*)&ot[w][rsel][col];
            f4 xv = *(const f4*)(xr + col);
            f4 ov;
            ov[0] = gelu_f(lv[0] + xv[0]);
            ov[1] = gelu_f(lv[1] + xv[1]);
            ov[2] = gelu_f(lv[2] + xv[2]);
            ov[3] = gelu_f(lv[3] + xv[3]);
            *(f4*)(outr + col) = ov;
        }
        __syncthreads();   // WAR before next r writes
    }
}

// ---------------------------------------------------------------------------
extern "C" void kernel_launch(void* const* d_in, const int* in_sizes, int n_in,
                              void* d_out, int out_size, void* d_ws, size_t ws_size,
                              hipStream_t stream)
{
    const float* x  = (const float*)d_in[0];
    const float* W1 = (const float*)d_in[1];
    const float* W2 = (const float*)d_in[2];
    const float* W3 = (const float*)d_in[3];
    const float* g1 = (const float*)d_in[4];
    const float* b1 = (const float*)d_in[5];
    const float* g2 = (const float*)d_in[6];
    const float* b2 = (const float*)d_in[7];
    const float* g3 = (const float*)d_in[8];
    const float* b3 = (const float*)d_in[9];
    const int* nidx = (const int*)d_in[10];
    float* out = (float*)d_out;

    char* ws = (char*)d_ws;
    u16* W1f = (u16*)(ws);                   //  32768 B
    u16* W2f = (u16*)(ws + 32768);           //  73728 B
    u16* W3f = (u16*)(ws + 106496);          //  32768 B
    u16* h1  = (u16*)(ws + 139264);          //  (NPTS+1)*64*2 = 25,600,128 B
    u16* h2  = (u16*)(ws + 139264 + 25600128);  // NPTS*64*2 = 25,600,000 B

    hipLaunchKernelGGL(k0_convw, dim3(144), dim3(256), 0, stream,
                       W1, W2, W3, W1f, W2f, W3f, h1);
    hipLaunchKernelGGL(k1_conv1, dim3(3125), dim3(256), 0, stream,
                       x, W1f, g1, b1, h1);
    hipLaunchKernelGGL(k2a_conv2, dim3(3125), dim3(256), 0, stream,
                       h1, W2f, g2, b2, nidx, h2);
    hipLaunchKernelGGL(k2b_conv3, dim3(3125), dim3(256), 0, stream,
                       h2, W3f, x, g3, b3, out);
}

// Round 8
// 250.094 us; speedup vs baseline: 1.2062x; 1.2062x over previous
//
#include <hip/hip_runtime.h>
#include <math.h>

// Problem constants
#define NPTS 200000
#define LNEPS 1e-6f

typedef unsigned short u16;
typedef unsigned int   u32;
typedef __attribute__((ext_vector_type(4))) float  f4;
typedef __attribute__((ext_vector_type(8))) short  s8;
typedef __attribute__((ext_vector_type(4))) short  s4;

__device__ __forceinline__ u16 f2b(float f) {
    union { float f; unsigned u; } v; v.f = f;
    unsigned r = v.u + 0x7fffu + ((v.u >> 16) & 1u);   // round-to-nearest-even
    return (u16)(r >> 16);
}
__device__ __forceinline__ float b2f(u16 v) {
    union { u32 u; float f; } t; t.u = (u32)v << 16; return t.f;
}

// tanh-form GELU via HW exp2/rcp (~1e-3 max dev from exact erf-GELU).
__device__ __forceinline__ float gelu_f(float v) {
    float u = v * (0.7978845608028654f + 0.035677408136300125f * v * v);
    u = fminf(u, 15.0f);
    float e = __builtin_amdgcn_exp2f(u * 2.8853900817779268f);  // exp(2u)
    return 0.5f * v * (1.0f + (e - 1.0f) * __builtin_amdgcn_rcpf(e + 1.0f));
}

// ---------------------------------------------------------------------------
// K0: repack weights to bf16 MFMA B-fragment order. (unchanged)
// B-frag: lane l holds B[k][n], n = 16*nt + (l&15), k = 32*ks + (l>>4)*8 + j.
// ---------------------------------------------------------------------------
__global__ __launch_bounds__(256) void k0_convw(
    const float* __restrict__ W1, const float* __restrict__ W2,
    const float* __restrict__ W3,
    u16* __restrict__ W1f, u16* __restrict__ W2f, u16* __restrict__ W3f,
    u16* __restrict__ h1)
{
    int t = blockIdx.x * 256 + threadIdx.x;
    if (t < 16384) {                       // W1f: nt(4) ks(8) l(64) j(8)
        int j = t & 7, l = (t >> 3) & 63, ks = (t >> 9) & 7, nt = t >> 12;
        int k = 32 * ks + (l >> 4) * 8 + j;
        int n = 16 * nt + (l & 15);
        W1f[t] = f2b(W1[k * 64 + n]);
    }
    if (t < 36864) {                       // W2f: kk(9) x { nt(4) ks(2) l(64) j(8) }
        int kk = t >> 12;
        int r = t & 4095;
        int j = r & 7, l = (r >> 3) & 63, ks = (r >> 9) & 1, nt = r >> 10;
        int k = 32 * ks + (l >> 4) * 8 + j;
        int n = 16 * nt + (l & 15);
        W2f[t] = f2b(W2[(kk * 64 + k) * 64 + n]);
    }
    if (t < 16384) {                       // W3f: nt(16) ks(2) l(64) j(8)
        int j = t & 7, l = (t >> 3) & 63, ks = (t >> 9) & 1, nt = t >> 10;
        int k = 32 * ks + (l >> 4) * 8 + j;
        int n = 16 * nt + (l & 15);
        W3f[t] = f2b(W3[k * 256 + n]);
    }
    if (t < 64) h1[(long)NPTS * 64 + t] = 0;   // sentinel zero row
}

// ---------------------------------------------------------------------------
// K1a: pure streaming cast x fp32 -> xb bf16.
// 2000 blocks x 256 threads x 25 f4-chunks each = 12,800,000 chunks exactly.
// No LDS, no barriers, tiny VGPR -> ~8 waves/SIMD, max read concurrency.
// ---------------------------------------------------------------------------
__global__ __launch_bounds__(256) void k1a_cast(
    const float* __restrict__ x, u16* __restrict__ xb)
{
    long gid = (long)blockIdx.x * 256 + threadIdx.x;   // 0..511999
    #pragma unroll 5
    for (int k = 0; k < 25; ++k) {
        long c = gid + (long)k * 512000;
        f4 v = *(const f4*)(x + c * 4);
        s4 b;
        b[0] = (short)f2b(v[0]); b[1] = (short)f2b(v[1]);
        b[2] = (short)f2b(v[2]); b[3] = (short)f2b(v[3]);
        *(s4*)(xb + c * 4) = b;
    }
}

// ---------------------------------------------------------------------------
// K1b: conv1 + LN + GELU -> h1 (bf16, [NPTS+1][64]).
// USE_XB=1: A-frags load directly from bf16 xb (1 s8/lane per ks, L3-hot).
// USE_XB=0 fallback: loads fp32 x and converts in-register.
// ---------------------------------------------------------------------------
template<int USE_XB>
__global__ __launch_bounds__(256) void k1b_conv1(
    const float* __restrict__ x, const u16* __restrict__ xb,
    const u16* __restrict__ W1f,
    const float* __restrict__ g1, const float* __restrict__ b1,
    u16* __restrict__ h1)
{
    int tid = threadIdx.x;
    int w = tid >> 6, l = tid & 63, lg = l >> 4, lr = l & 15;
    long base = (long)blockIdx.x * 64 + w * 16;
    long row0 = base + lr;

    s8 af[8];
    if (USE_XB) {
        const u16* xr = xb + row0 * 256;
        #pragma unroll
        for (int ks = 0; ks < 8; ++ks)
            af[ks] = *(const s8*)(xr + 32 * ks + lg * 8);
    } else {
        const float* xr = x + row0 * 256;
        #pragma unroll
        for (int ks = 0; ks < 8; ++ks) {
            f4 a0 = *(const f4*)(xr + 32 * ks + lg * 8);
            f4 a1 = *(const f4*)(xr + 32 * ks + lg * 8 + 4);
            s8 a;
            a[0] = (short)f2b(a0[0]); a[1] = (short)f2b(a0[1]);
            a[2] = (short)f2b(a0[2]); a[3] = (short)f2b(a0[3]);
            a[4] = (short)f2b(a1[0]); a[5] = (short)f2b(a1[1]);
            a[6] = (short)f2b(a1[2]); a[7] = (short)f2b(a1[3]);
            af[ks] = a;
        }
    }

    f4 acc[4] = {};
    #pragma unroll
    for (int ks = 0; ks < 8; ++ks) {
        #pragma unroll
        for (int nt = 0; nt < 4; ++nt) {
            s8 b = *(const s8*)(W1f + ((nt * 8 + ks) * 64 + l) * 8);
            acc[nt] = __builtin_amdgcn_mfma_f32_16x16x32_bf16(af[ks], b, acc[nt], 0, 0, 0);
        }
    }

    #pragma unroll
    for (int r = 0; r < 4; ++r) {
        float sv = 0.f, qv = 0.f;
        #pragma unroll
        for (int nt = 0; nt < 4; ++nt) { float v = acc[nt][r]; sv += v; qv += v * v; }
        #pragma unroll
        for (int m = 1; m < 16; m <<= 1) { sv += __shfl_xor(sv, m); qv += __shfl_xor(qv, m); }
        float mu  = sv * (1.0f / 64.0f);
        float var = qv * (1.0f / 64.0f) - mu * mu;
        float rs  = rsqrtf(var + LNEPS);
        long row = base + lg * 4 + r;
        #pragma unroll
        for (int nt = 0; nt < 4; ++nt) {
            int col = 16 * nt + lr;
            float v = (acc[nt][r] - mu) * rs * g1[col] + b1[col];
            h1[row * 64 + col] = f2b(gelu_f(v));
        }
    }
}

// ---------------------------------------------------------------------------
// K2a: gather + conv2 + LN + GELU -> h2 (register-gather form).
// ---------------------------------------------------------------------------
__global__ __launch_bounds__(256, 4) void k2a_conv2(
    const u16* __restrict__ h1, const u16* __restrict__ W2f,
    const float* __restrict__ g2, const float* __restrict__ b2,
    const int* __restrict__ nidx, u16* __restrict__ h2)
{
    int tid = threadIdx.x;
    int w = tid >> 6, l = tid & 63, lg = l >> 4, lr = l & 15;
    long base = (long)blockIdx.x * 64 + w * 16;
    long rowa = base + lr;

    int idxs[9];
    #pragma unroll
    for (int k = 0; k < 9; ++k) idxs[k] = nidx[(long)k * NPTS + rowa];

    s8 afr[9][2];
    #pragma unroll
    for (int k = 0; k < 9; ++k) {
        const u16* arow = h1 + (long)idxs[k] * 64;
        afr[k][0] = *(const s8*)(arow + lg * 8);
        afr[k][1] = *(const s8*)(arow + 32 + lg * 8);
    }

    f4 acc2[4] = {};
    #pragma unroll
    for (int k = 0; k < 9; ++k) {
        #pragma unroll
        for (int ks = 0; ks < 2; ++ks) {
            #pragma unroll
            for (int nt = 0; nt < 4; ++nt) {
                s8 b = *(const s8*)(W2f + (long)k * 4096 + ((nt * 2 + ks) * 64 + l) * 8);
                acc2[nt] = __builtin_amdgcn_mfma_f32_16x16x32_bf16(afr[k][ks], b, acc2[nt], 0, 0, 0);
            }
        }
    }

    #pragma unroll
    for (int r = 0; r < 4; ++r) {
        float sv = 0.f, qv = 0.f;
        #pragma unroll
        for (int nt = 0; nt < 4; ++nt) { float v = acc2[nt][r]; sv += v; qv += v * v; }
        #pragma unroll
        for (int m = 1; m < 16; m <<= 1) { sv += __shfl_xor(sv, m); qv += __shfl_xor(qv, m); }
        float mu  = sv * (1.0f / 64.0f);
        float var = qv * (1.0f / 64.0f) - mu * mu;
        float rs  = rsqrtf(var + LNEPS);
        long row = base + lg * 4 + r;
        #pragma unroll
        for (int nt = 0; nt < 4; ++nt) {
            int col = 16 * nt + lr;
            float v = (acc2[nt][r] - mu) * rs * g2[col] + b2[col];
            h2[row * 64 + col] = f2b(gelu_f(v));
        }
    }
}

// ---------------------------------------------------------------------------
// K2b: conv3 + LN(256) + residual + GELU -> out.
// USE_XB=1: residual from bf16 xb (halves this kernel's x traffic).
// ---------------------------------------------------------------------------
template<int USE_XB>
__global__ __launch_bounds__(256, 3) void k2b_conv3(
    const u16* __restrict__ h2, const u16* __restrict__ W3f,
    const float* __restrict__ x, const u16* __restrict__ xb,
    const float* __restrict__ g3, const float* __restrict__ b3,
    float* __restrict__ out)
{
    __shared__ __align__(16) float ot[4][4][264];   // [wave][row][col], +8 pad
    int tid = threadIdx.x;
    int w = tid >> 6, l = tid & 63, lg = l >> 4, lr = l & 15;
    long base = (long)blockIdx.x * 64 + w * 16;

    const u16* arow = h2 + (base + lr) * 64;
    s8 a0 = *(const s8*)(arow + lg * 8);
    s8 a1 = *(const s8*)(arow + 32 + lg * 8);

    f4 acc3[16] = {};
    #pragma unroll
    for (int nt = 0; nt < 16; ++nt) {
        s8 b0 = *(const s8*)(W3f + ((nt * 2 + 0) * 64 + l) * 8);
        s8 b1 = *(const s8*)(W3f + ((nt * 2 + 1) * 64 + l) * 8);
        acc3[nt] = __builtin_amdgcn_mfma_f32_16x16x32_bf16(a0, b0, acc3[nt], 0, 0, 0);
        acc3[nt] = __builtin_amdgcn_mfma_f32_16x16x32_bf16(a1, b1, acc3[nt], 0, 0, 0);
    }

    #pragma unroll
    for (int r = 0; r < 4; ++r) {
        float sv = 0.f, qv = 0.f;
        #pragma unroll
        for (int nt = 0; nt < 16; ++nt) { float v = acc3[nt][r]; sv += v; qv += v * v; }
        #pragma unroll
        for (int m = 1; m < 16; m <<= 1) { sv += __shfl_xor(sv, m); qv += __shfl_xor(qv, m); }
        float mu  = sv * (1.0f / 256.0f);
        float var = qv * (1.0f / 256.0f) - mu * mu;
        float rs  = rsqrtf(var + LNEPS);

        #pragma unroll
        for (int nt = 0; nt < 16; ++nt) {
            int col = 16 * nt + lr;
            ot[w][lg][col] = (acc3[nt][r] - mu) * rs * g3[col] + b3[col];
        }
        __syncthreads();

        int rsel = l >> 4;
        long gr = (long)blockIdx.x * 64 + w * 16 + rsel * 4 + r;
        float* outr = out + gr * 256;
        int c0 = (l & 15) * 4;
        #pragma unroll
        for (int c = 0; c < 4; ++c) {
            int col = c0 + 64 * c;
            f4 lv = *(const f4*)&ot[w][rsel][col];
            f4 xv;
            if (USE_XB) {
                s4 xq = *(const s4*)(xb + gr * 256 + col);
                xv[0] = b2f((u16)xq[0]); xv[1] = b2f((u16)xq[1]);
                xv[2] = b2f((u16)xq[2]); xv[3] = b2f((u16)xq[3]);
            } else {
                xv = *(const f4*)(x + gr * 256 + col);
            }
            f4 ov;
            ov[0] = gelu_f(lv[0] + xv[0]);
            ov[1] = gelu_f(lv[1] + xv[1]);
            ov[2] = gelu_f(lv[2] + xv[2]);
            ov[3] = gelu_f(lv[3] + xv[3]);
            *(f4*)(outr + col) = ov;
        }
        __syncthreads();   // WAR before next r writes
    }
}

// ---------------------------------------------------------------------------
extern "C" void kernel_launch(void* const* d_in, const int* in_sizes, int n_in,
                              void* d_out, int out_size, void* d_ws, size_t ws_size,
                              hipStream_t stream)
{
    const float* x  = (const float*)d_in[0];
    const float* W1 = (const float*)d_in[1];
    const float* W2 = (const float*)d_in[2];
    const float* W3 = (const float*)d_in[3];
    const float* g1 = (const float*)d_in[4];
    const float* b1 = (const float*)d_in[5];
    const float* g2 = (const float*)d_in[6];
    const float* b2 = (const float*)d_in[7];
    const float* g3 = (const float*)d_in[8];
    const float* b3 = (const float*)d_in[9];
    const int* nidx = (const int*)d_in[10];
    float* out = (float*)d_out;

    char* ws = (char*)d_ws;
    u16* W1f = (u16*)(ws);                        //  32768 B
    u16* W2f = (u16*)(ws + 32768);                //  73728 B
    u16* W3f = (u16*)(ws + 106496);               //  32768 B
    u16* h1  = (u16*)(ws + 139264);               //  (NPTS+1)*64*2 = 25,600,128 B
    u16* h2  = (u16*)(ws + 139264 + 25600128);    //  NPTS*64*2    = 25,600,000 B
    u16* xb  = (u16*)(ws + 139264 + 25600128 + 25600000);  // NPTS*256*2 = 102,400,000 B
    const size_t WS_NEEDED = 139264UL + 25600128UL + 25600000UL + 102400000UL;

    hipLaunchKernelGGL(k0_convw, dim3(144), dim3(256), 0, stream,
                       W1, W2, W3, W1f, W2f, W3f, h1);

    if (ws_size >= WS_NEEDED) {
        hipLaunchKernelGGL(k1a_cast, dim3(2000), dim3(256), 0, stream, x, xb);
        hipLaunchKernelGGL((k1b_conv1<1>), dim3(3125), dim3(256), 0, stream,
                           x, xb, W1f, g1, b1, h1);
        hipLaunchKernelGGL(k2a_conv2, dim3(3125), dim3(256), 0, stream,
                           h1, W2f, g2, b2, nidx, h2);
        hipLaunchKernelGGL((k2b_conv3<1>), dim3(3125), dim3(256), 0, stream,
                           h2, W3f, x, xb, g3, b3, out);
    } else {
        hipLaunchKernelGGL((k1b_conv1<0>), dim3(3125), dim3(256), 0, stream,
                           x, xb, W1f, g1, b1, h1);
        hipLaunchKernelGGL(k2a_conv2, dim3(3125), dim3(256), 0, stream,
                           h1, W2f, g2, b2, nidx, h2);
        hipLaunchKernelGGL((k2b_conv3<0>), dim3(3125), dim3(256), 0, stream,
                           h2, W3f, x, xb, g3, b3, out);
    }
}

// Round 9
// 219.597 us; speedup vs baseline: 1.3738x; 1.1389x over previous
//
#include <hip/hip_runtime.h>
#include <math.h>

// Problem constants
#define NPTS 200000
#define LNEPS 1e-6f

typedef unsigned short u16;
typedef unsigned int   u32;
typedef __attribute__((ext_vector_type(4))) float  f4;
typedef __attribute__((ext_vector_type(8))) short  s8;
typedef __attribute__((ext_vector_type(4))) short  s4;

__device__ __forceinline__ u16 f2b(float f) {
    union { float f; unsigned u; } v; v.f = f;
    unsigned r = v.u + 0x7fffu + ((v.u >> 16) & 1u);   // round-to-nearest-even
    return (u16)(r >> 16);
}

// tanh-form GELU via HW exp2/rcp (~1e-3 max dev from exact erf-GELU).
__device__ __forceinline__ float gelu_f(float v) {
    float u = v * (0.7978845608028654f + 0.035677408136300125f * v * v);
    u = fminf(u, 15.0f);
    float e = __builtin_amdgcn_exp2f(u * 2.8853900817779268f);  // exp(2u)
    return 0.5f * v * (1.0f + (e - 1.0f) * __builtin_amdgcn_rcpf(e + 1.0f));
}

// ---------------------------------------------------------------------------
// K0: repack weights to bf16 MFMA B-fragment order.
// B-frag: lane l holds B[k][n], n = 16*nt + (l&15), k = 32*ks + (l>>4)*8 + j.
// Storage: frag[((nt*KS + ks)*64 + l)*8 + j]. Also zeroes sentinel h1 row.
// ---------------------------------------------------------------------------
__global__ __launch_bounds__(256) void k0_convw(
    const float* __restrict__ W1, const float* __restrict__ W2,
    const float* __restrict__ W3,
    u16* __restrict__ W1f, u16* __restrict__ W2f, u16* __restrict__ W3f,
    u16* __restrict__ h1)
{
    int t = blockIdx.x * 256 + threadIdx.x;
    if (t < 16384) {                       // W1f: nt(4) ks(8) l(64) j(8)
        int j = t & 7, l = (t >> 3) & 63, ks = (t >> 9) & 7, nt = t >> 12;
        int k = 32 * ks + (l >> 4) * 8 + j;
        int n = 16 * nt + (l & 15);
        W1f[t] = f2b(W1[k * 64 + n]);
    }
    if (t < 36864) {                       // W2f: kk(9) x { nt(4) ks(2) l(64) j(8) }
        int kk = t >> 12;
        int r = t & 4095;
        int j = r & 7, l = (r >> 3) & 63, ks = (r >> 9) & 1, nt = r >> 10;
        int k = 32 * ks + (l >> 4) * 8 + j;
        int n = 16 * nt + (l & 15);
        W2f[t] = f2b(W2[(kk * 64 + k) * 64 + n]);
    }
    if (t < 16384) {                       // W3f: nt(16) ks(2) l(64) j(8)
        int j = t & 7, l = (t >> 3) & 63, ks = (t >> 9) & 1, nt = t >> 10;
        int k = 32 * ks + (l >> 4) * 8 + j;
        int n = 16 * nt + (l & 15);
        W3f[t] = f2b(W3[k * 256 + n]);
    }
    if (t < 64) h1[(long)NPTS * 64 + t] = 0;   // sentinel zero row
}

// ---------------------------------------------------------------------------
// K1: conv1 (x @ W1) + LN + GELU -> h1 (bf16, [NPTS+1][64])
// R1 direct-load form (fast): 16 hoisted f4 x-loads -> convert -> MFMA.
// New: h1 stored via small per-wave LDS transpose -> 2 coalesced 1KB/wave
// b128 stores instead of 16 scattered u16 stores per thread.
// ---------------------------------------------------------------------------
__global__ __launch_bounds__(256) void k1_conv1(
    const float* __restrict__ x, const u16* __restrict__ W1f,
    const float* __restrict__ g1, const float* __restrict__ b1,
    u16* __restrict__ h1)
{
    __shared__ __align__(16) u16 hs[4][16][72];   // 9 KB, +8 pad
    int tid = threadIdx.x;
    int w = tid >> 6, l = tid & 63, lg = l >> 4, lr = l & 15;
    long base = (long)blockIdx.x * 64 + w * 16;
    const float* xrow = x + (base + lr) * 256;

    f4 xa[16];
    #pragma unroll
    for (int ks = 0; ks < 8; ++ks) {
        xa[2 * ks]     = *(const f4*)(xrow + 32 * ks + lg * 8);
        xa[2 * ks + 1] = *(const f4*)(xrow + 32 * ks + lg * 8 + 4);
    }

    f4 acc[4] = {};
    #pragma unroll
    for (int ks = 0; ks < 8; ++ks) {
        f4 a0 = xa[2 * ks], a1 = xa[2 * ks + 1];
        s8 a;
        a[0] = (short)f2b(a0[0]); a[1] = (short)f2b(a0[1]);
        a[2] = (short)f2b(a0[2]); a[3] = (short)f2b(a0[3]);
        a[4] = (short)f2b(a1[0]); a[5] = (short)f2b(a1[1]);
        a[6] = (short)f2b(a1[2]); a[7] = (short)f2b(a1[3]);
        #pragma unroll
        for (int nt = 0; nt < 4; ++nt) {
            s8 b = *(const s8*)(W1f + ((nt * 8 + ks) * 64 + l) * 8);
            acc[nt] = __builtin_amdgcn_mfma_f32_16x16x32_bf16(a, b, acc[nt], 0, 0, 0);
        }
    }

    // LN(64) + GELU -> LDS (bf16).  D layout: col = 16*nt + lr, row = lg*4+r.
    #pragma unroll
    for (int r = 0; r < 4; ++r) {
        float sv = 0.f, qv = 0.f;
        #pragma unroll
        for (int nt = 0; nt < 4; ++nt) { float v = acc[nt][r]; sv += v; qv += v * v; }
        #pragma unroll
        for (int m = 1; m < 16; m <<= 1) { sv += __shfl_xor(sv, m); qv += __shfl_xor(qv, m); }
        float mu  = sv * (1.0f / 64.0f);
        float var = qv * (1.0f / 64.0f) - mu * mu;
        float rs  = rsqrtf(var + LNEPS);
        int row16 = lg * 4 + r;
        #pragma unroll
        for (int nt = 0; nt < 4; ++nt) {
            int col = 16 * nt + lr;
            float v = (acc[nt][r] - mu) * rs * g1[col] + b1[col];
            hs[w][row16][col] = f2b(gelu_f(v));
        }
    }
    __syncthreads();

    // coalesced store: lane l -> row16 = it*8 + (l>>3), chunk = l&7 (8 u16).
    // 64 lanes x 16B = 1KB contiguous per wave per iteration.
    #pragma unroll
    for (int it = 0; it < 2; ++it) {
        int row16 = it * 8 + (l >> 3);
        int ch = l & 7;
        s8 v = *(const s8*)&hs[w][row16][ch * 8];
        *(s8*)(h1 + (base + row16) * 64 + ch * 8) = v;
    }
}

// ---------------------------------------------------------------------------
// K2a: gather + conv2 + LN + GELU -> h2 (register-gather form, unchanged).
// ---------------------------------------------------------------------------
__global__ __launch_bounds__(256, 4) void k2a_conv2(
    const u16* __restrict__ h1, const u16* __restrict__ W2f,
    const float* __restrict__ g2, const float* __restrict__ b2,
    const int* __restrict__ nidx, u16* __restrict__ h2)
{
    int tid = threadIdx.x;
    int w = tid >> 6, l = tid & 63, lg = l >> 4, lr = l & 15;
    long base = (long)blockIdx.x * 64 + w * 16;
    long rowa = base + lr;

    int idxs[9];
    #pragma unroll
    for (int k = 0; k < 9; ++k) idxs[k] = nidx[(long)k * NPTS + rowa];

    s8 afr[9][2];
    #pragma unroll
    for (int k = 0; k < 9; ++k) {
        const u16* arow = h1 + (long)idxs[k] * 64;
        afr[k][0] = *(const s8*)(arow + lg * 8);
        afr[k][1] = *(const s8*)(arow + 32 + lg * 8);
    }

    f4 acc2[4] = {};
    #pragma unroll
    for (int k = 0; k < 9; ++k) {
        #pragma unroll
        for (int ks = 0; ks < 2; ++ks) {
            #pragma unroll
            for (int nt = 0; nt < 4; ++nt) {
                s8 b = *(const s8*)(W2f + (long)k * 4096 + ((nt * 2 + ks) * 64 + l) * 8);
                acc2[nt] = __builtin_amdgcn_mfma_f32_16x16x32_bf16(afr[k][ks], b, acc2[nt], 0, 0, 0);
            }
        }
    }

    #pragma unroll
    for (int r = 0; r < 4; ++r) {
        float sv = 0.f, qv = 0.f;
        #pragma unroll
        for (int nt = 0; nt < 4; ++nt) { float v = acc2[nt][r]; sv += v; qv += v * v; }
        #pragma unroll
        for (int m = 1; m < 16; m <<= 1) { sv += __shfl_xor(sv, m); qv += __shfl_xor(qv, m); }
        float mu  = sv * (1.0f / 64.0f);
        float var = qv * (1.0f / 64.0f) - mu * mu;
        float rs  = rsqrtf(var + LNEPS);
        long row = base + lg * 4 + r;
        #pragma unroll
        for (int nt = 0; nt < 4; ++nt) {
            int col = 16 * nt + lr;
            float v = (acc2[nt][r] - mu) * rs * g2[col] + b2[col];
            h2[row * 64 + col] = f2b(gelu_f(v));
        }
    }
}

// ---------------------------------------------------------------------------
// K2b: conv3 (h2 @ W3) + LN(256) + residual(x) + GELU -> out.
// LDS-epilogue form (unchanged from R3): coalesced f4 x-read / out-write.
// ---------------------------------------------------------------------------
__global__ __launch_bounds__(256, 3) void k2b_conv3(
    const u16* __restrict__ h2, const u16* __restrict__ W3f,
    const float* __restrict__ x,
    const float* __restrict__ g3, const float* __restrict__ b3,
    float* __restrict__ out)
{
    __shared__ __align__(16) float ot[4][4][264];   // [wave][row][col], +8 pad
    int tid = threadIdx.x;
    int w = tid >> 6, l = tid & 63, lg = l >> 4, lr = l & 15;
    long base = (long)blockIdx.x * 64 + w * 16;

    const u16* arow = h2 + (base + lr) * 64;
    s8 a0 = *(const s8*)(arow + lg * 8);
    s8 a1 = *(const s8*)(arow + 32 + lg * 8);

    f4 acc3[16] = {};
    #pragma unroll
    for (int nt = 0; nt < 16; ++nt) {
        s8 b0 = *(const s8*)(W3f + ((nt * 2 + 0) * 64 + l) * 8);
        s8 b1 = *(const s8*)(W3f + ((nt * 2 + 1) * 64 + l) * 8);
        acc3[nt] = __builtin_amdgcn_mfma_f32_16x16x32_bf16(a0, b0, acc3[nt], 0, 0, 0);
        acc3[nt] = __builtin_amdgcn_mfma_f32_16x16x32_bf16(a1, b1, acc3[nt], 0, 0, 0);
    }

    #pragma unroll
    for (int r = 0; r < 4; ++r) {
        float sv = 0.f, qv = 0.f;
        #pragma unroll
        for (int nt = 0; nt < 16; ++nt) { float v = acc3[nt][r]; sv += v; qv += v * v; }
        #pragma unroll
        for (int m = 1; m < 16; m <<= 1) { sv += __shfl_xor(sv, m); qv += __shfl_xor(qv, m); }
        float mu  = sv * (1.0f / 256.0f);
        float var = qv * (1.0f / 256.0f) - mu * mu;
        float rs  = rsqrtf(var + LNEPS);

        #pragma unroll
        for (int nt = 0; nt < 16; ++nt) {
            int col = 16 * nt + lr;
            ot[w][lg][col] = (acc3[nt][r] - mu) * rs * g3[col] + b3[col];
        }
        __syncthreads();

        int rsel = l >> 4;
        long gr = (long)blockIdx.x * 64 + w * 16 + rsel * 4 + r;
        const float* xr = x + gr * 256;
        float* outr = out + gr * 256;
        int c0 = (l & 15) * 4;
        #pragma unroll
        for (int c = 0; c < 4; ++c) {
            int col = c0 + 64 * c;
            f4 lv = *(const f4*)&ot[w][rsel][col];
            f4 xv = *(const f4*)(xr + col);
            f4 ov;
            ov[0] = gelu_f(lv[0] + xv[0]);
            ov[1] = gelu_f(lv[1] + xv[1]);
            ov[2] = gelu_f(lv[2] + xv[2]);
            ov[3] = gelu_f(lv[3] + xv[3]);
            *(f4*)(outr + col) = ov;
        }
        __syncthreads();   // WAR before next r writes
    }
}

// ---------------------------------------------------------------------------
extern "C" void kernel_launch(void* const* d_in, const int* in_sizes, int n_in,
                              void* d_out, int out_size, void* d_ws, size_t ws_size,
                              hipStream_t stream)
{
    const float* x  = (const float*)d_in[0];
    const float* W1 = (const float*)d_in[1];
    const float* W2 = (const float*)d_in[2];
    const float* W3 = (const float*)d_in[3];
    const float* g1 = (const float*)d_in[4];
    const float* b1 = (const float*)d_in[5];
    const float* g2 = (const float*)d_in[6];
    const float* b2 = (const float*)d_in[7];
    const float* g3 = (const float*)d_in[8];
    const float* b3 = (const float*)d_in[9];
    const int* nidx = (const int*)d_in[10];
    float* out = (float*)d_out;

    char* ws = (char*)d_ws;
    u16* W1f = (u16*)(ws);                   //  32768 B
    u16* W2f = (u16*)(ws + 32768);           //  73728 B
    u16* W3f = (u16*)(ws + 106496);          //  32768 B
    u16* h1  = (u16*)(ws + 139264);          //  (NPTS+1)*64*2 = 25,600,128 B
    u16* h2  = (u16*)(ws + 139264 + 25600128);  // NPTS*64*2 = 25,600,000 B

    hipLaunchKernelGGL(k0_convw, dim3(144), dim3(256), 0, stream,
                       W1, W2, W3, W1f, W2f, W3f, h1);
    hipLaunchKernelGGL(k1_conv1, dim3(3125), dim3(256), 0, stream,
                       x, W1f, g1, b1, h1);
    hipLaunchKernelGGL(k2a_conv2, dim3(3125), dim3(256), 0, stream,
                       h1, W2f, g2, b2, nidx, h2);
    hipLaunchKernelGGL(k2b_conv3, dim3(3125), dim3(256), 0, stream,
                       h2, W3f, x, g3, b3, out);
}